// Round 5
// baseline (429.974 us; speedup 1.0000x reference)
//
#include <hip/hip_runtime.h>
#include <hip/hip_bf16.h>

// ---------------------------------------------------------------------------
// BF_NIR_conv, round 5: 4-tile pipelined blocks, weights resident, per-tile
// globals prefetched one tile ahead.
//   U[pos][256] = featc[:,pos] @ W1[0:256,:]   (precomputed bf16; row 16387=0)
//   Per tile (1x16 pixel row, 64 h1-rows = 16 pix x 4 branches):
//     h1^T[n][m] = sum_{k<128} W1[256+k][n]*hr[pix(m)][k]
//                + relY(m)*W1[384][n] + relX(m)*W1[385][n] + b1[n]  (Wx MFMA)
//                + U[spos(m)][n]                                    (C/D add)
//     h1 = relu -> LDS; h2 = relu(h1@W2+b2); pred = h2@W3+b3
//     out = softmax(gc)-weighted sum over branches
// ---------------------------------------------------------------------------

using bf16x8 = __attribute__((ext_vector_type(8))) __bf16;
using f32x4  = __attribute__((ext_vector_type(4))) float;

__device__ __forceinline__ float bf2f(unsigned short u){
  unsigned int x = ((unsigned int)u) << 16;
  return __builtin_bit_cast(float, x);
}
__device__ __forceinline__ unsigned short f2bf(float f){
  unsigned int x = __builtin_bit_cast(unsigned int, f);
  unsigned int r = x + 0x7fffu + ((x >> 16) & 1u);
  return (unsigned short)(r >> 16);
}
__device__ __forceinline__ bf16x8 ld8(const ushort* p){
  uint4 r = *(const uint4*)p;
  return __builtin_bit_cast(bf16x8, r);
}

struct RowMeta { int valid, ix; float relY, relX; int spos; };
__device__ __forceinline__ RowMeta row_meta(int Y, int X, int br){
  int ivx = br >> 1, ivy = br & 1;   // branch: (vx,vy)=(-,-),(-,+),(+,-),(+,+)
  int validY, iy; float relY;
  if (ivx == 0){ validY = (Y >= 1);   iy = (Y-1) >> 1; relY = (Y & 1) ?  0.5f :  1.5f; }
  else         { validY = (Y <= 254); iy = (Y+1) >> 1; relY = (Y & 1) ? -1.5f : -0.5f; }
  int validX, ix; float relX;
  if (ivy == 0){ validX = (X >= 1);   ix = (X-1) >> 1; relX = (X & 1) ?  0.5f :  1.5f; }
  else         { validX = (X <= 254); ix = (X+1) >> 1; relX = (X & 1) ? -1.5f : -0.5f; }
  RowMeta r;
  r.valid = validY && validX;
  r.ix = ix;
  if (r.valid){ r.relY = relY; r.relX = relX; r.spos = iy*128 + ix; }
  else { r.relY = (float)Y + 0.5f - 128.0f; r.relX = (float)X + 0.5f - 128.0f; r.spos = -1; }
  return r;
}

// --- kernel 0: weights -> bf16 N-major; all READS coalesced ------------------
__global__ __launch_bounds__(256) void convert_weights(
    const float* __restrict__ W1, const float* __restrict__ b1,
    const float* __restrict__ W2, const float* __restrict__ W3,
    ushort* __restrict__ W1t,   // [256][384]
    ushort* __restrict__ W2t,   // [128][256]
    ushort* __restrict__ W3t,   // [32][128]
    ushort* __restrict__ Wx,    // [256][32]: s0=W1[384][n], s1=W1[385][n], s2=b1[n]
    ushort* __restrict__ Ubz)   // Ub row 16387 (zeros)
{
  int b = blockIdx.x, t = threadIdx.x;
  if (b < 384){
    W1t[t*384 + b] = f2bf(W1[b*256 + t]);
  } else if (b < 386){
    Wx[t*32 + (b - 384)] = f2bf(W1[b*256 + t]);
  } else if (b == 386){
    Wx[t*32 + 2] = f2bf(b1[t]);
    #pragma unroll
    for (int j=3; j<32; j++) Wx[t*32 + j] = 0;
  } else if (b < 387 + 256){
    int k = b - 387;
    if (t < 128) W2t[t*256 + k] = f2bf(W2[k*128 + t]);
  } else if (b < 643 + 128){
    int k = b - 643;
    if (t < 32) W3t[t*128 + k] = f2bf(W3[k*32 + t]);
  } else {
    Ubz[t] = 0;
  }
}

// --- kernel 1: U GEMM. M-tile 32, N-half 128, grid 1024. --------------------
__global__ __launch_bounds__(256) void stage1_gemm(
    const float* __restrict__ src0, const float* __restrict__ src1,  // lr_guide, feat
    const ushort* __restrict__ W1t,
    ushort* __restrict__ outp)                 // [16384][256]
{
  __shared__ ushort A[32*136];
  const int t = threadIdx.x;
  const int w = t >> 6, lane = t & 63, quad = lane >> 4, l15 = lane & 15;
  const int pos0  = (blockIdx.x >> 1) * 32;
  const int nside = (blockIdx.x & 1) * 128;
  const int mt = w >> 1;
  const int ntb = (w & 1) * 4;

  f32x4 acc[4];
  #pragma unroll
  for (int nt=0; nt<4; nt++) acc[nt] = f32x4{0.f,0.f,0.f,0.f};

  for (int h=0; h<2; h++){
    const float* src = h ? src1 : src0;
    #pragma unroll
    for (int j=0; j<4; j++){                 // vectorized staging: float4 loads
      int k  = (t >> 3) + j*32;
      int mm = (t & 7) * 4;
      float4 v = *(const float4*)(src + (size_t)k*16384 + pos0 + mm);
      A[(mm+0)*136 + k] = f2bf(v.x);
      A[(mm+1)*136 + k] = f2bf(v.y);
      A[(mm+2)*136 + k] = f2bf(v.z);
      A[(mm+3)*136 + k] = f2bf(v.w);
    }
    __syncthreads();
    #pragma unroll
    for (int kt=0; kt<4; kt++){
      bf16x8 a = ld8(&A[(mt*16 + l15)*136 + kt*32 + quad*8]);
      #pragma unroll
      for (int nt=0; nt<4; nt++){
        bf16x8 b = ld8(&W1t[(size_t)(nside + (ntb+nt)*16 + l15)*384 + h*128 + kt*32 + quad*8]);
        acc[nt] = __builtin_amdgcn_mfma_f32_16x16x32_bf16(a, b, acc[nt], 0,0,0);
      }
    }
    __syncthreads();
  }
  #pragma unroll
  for (int nt=0; nt<4; nt++){
    int n = nside + (ntb+nt)*16 + l15;
    #pragma unroll
    for (int r=0; r<4; r++){
      int mm = mt*16 + quad*4 + r;
      outp[(size_t)(pos0 + mm)*256 + n] = f2bf(acc[nt][r]);
    }
  }
}

// --- kernel 2: fused main, 4 pipelined tiles per block -----------------------
__global__ __launch_bounds__(256, 4) void main_fused(
    const float* __restrict__ feat,      // [128][16384]
    const float* __restrict__ hr_guide,  // [128][65536]
    const float* __restrict__ b2v,
    const float* __restrict__ b3v,
    const ushort* __restrict__ Ub,       // [16388][256] bf16 (row 16387 zero)
    const ushort* __restrict__ W1t,      // [256][384] bf16 (N-major)
    const ushort* __restrict__ Wx,       // [256][32] rel/bias rows
    const ushort* __restrict__ W2t,      // [128][256] bf16 (N-major)
    const ushort* __restrict__ W3t,      // [32][128]  bf16 (N-major)
    float* __restrict__ outp)            // [32][65536]
{
  __shared__ __align__(16) ushort A1[64*264];   // h1 (stride 264); h2 aliases (stride 136)
  __shared__ __align__(16) ushort Ahr[16*136];  // hr tile [pix][ch]
  __shared__ float gcs[64];
  __shared__ float wgt[2][64];

  const int t = threadIdx.x;
  const int w = t >> 6, lane = t & 63, quad = lane >> 4, l15 = lane & 15;
  const int Y0 = (blockIdx.x >> 4) * 4;
  const int X0 = (blockIdx.x & 15) << 4;

  // ---- tile-invariant weight fragments (loaded once, live across tiles) ----
  bf16x8 a1f[4][4];   // W1t rows n = w*64+i*16+l15, k = 256+kt*32+quad*8
  bf16x8 a4f[4];      // Wx rel/bias rows
  bf16x8 b2f[8][2];   // W2
  #pragma unroll
  for (int i=0; i<4; i++){
    int n = w*64 + i*16 + l15;
    #pragma unroll
    for (int kt=0; kt<4; kt++)
      a1f[i][kt] = ld8(&W1t[(size_t)n*384 + 256 + kt*32 + quad*8]);
    a4f[i] = ld8(&Wx[(size_t)n*32 + quad*8]);
  }
  #pragma unroll
  for (int kt=0; kt<8; kt++)
    #pragma unroll
    for (int nt=0; nt<2; nt++)
      b2f[kt][nt] = ld8(&W2t[(size_t)(w*32 + nt*16 + l15)*256 + kt*32 + quad*8]);

  // ---- per-tile prefetch state ----
  RowMeta rmct[4];
  uint2   u4v[4][4];       // [i][ct] U-row slices in C/D layout cols
  float4  hrv[2];
  float   gfa[3], gfb[3];  // gc factors
  int     gvalid = 0;

  auto prefetch_tile = [&](int Ycur){
    int urow[4];
    #pragma unroll
    for (int ct=0; ct<4; ct++){
      int m = 16*ct + l15;
      rmct[ct] = row_meta(Ycur, X0 + (m>>2), m & 3);
      urow[ct] = rmct[ct].spos >= 0 ? rmct[ct].spos : 16387;
    }
    #pragma unroll
    for (int i=0; i<4; i++){
      int nc = w*64 + i*16 + quad*4;
      #pragma unroll
      for (int ct=0; ct<4; ct++)
        u4v[i][ct] = *(const uint2*)&Ub[(size_t)urow[ct]*256 + nc];
    }
    #pragma unroll
    for (int i2=0; i2<2; i2++){
      int id = i2*256 + t;
      hrv[i2] = *(const float4*)(hr_guide + (size_t)(id>>2)*65536 + Ycur*256 + X0 + (id&3)*4);
    }
    if (t < 64){
      RowMeta g = row_meta(Ycur, X0 + (t>>2), t & 3);
      gvalid = g.spos >= 0;
      int sp = gvalid ? g.spos : 0;
      int bpos = (Ycur>>1)*128 + ((X0 + (t>>2)) >> 1);
      #pragma unroll
      for (int cc=0; cc<3; cc++){
        gfa[cc] = feat[(size_t)(124+cc)*16384 + bpos];
        gfb[cc] = feat[(size_t)(124+cc)*16384 + sp];
      }
    }
  };
  auto stage_tile = [&](){
    #pragma unroll
    for (int i2=0; i2<2; i2++){
      int id = i2*256 + t;
      int ch = id >> 2, xq = id & 3;
      float4 v = hrv[i2];
      Ahr[(xq*4+0)*136 + ch] = f2bf(v.x);
      Ahr[(xq*4+1)*136 + ch] = f2bf(v.y);
      Ahr[(xq*4+2)*136 + ch] = f2bf(v.z);
      Ahr[(xq*4+3)*136 + ch] = f2bf(v.w);
    }
    if (t < 64)
      gcs[t] = gvalid ? (gfa[0]*gfb[0] + gfa[1]*gfb[1] + gfa[2]*gfb[2]) : 0.0f;
  };

  // ---- prologue: tile 0 ----
  prefetch_tile(Y0);
  stage_tile();
  __syncthreads();
  if (t < 16){
    float g0 = gcs[t*4+0], g1 = gcs[t*4+1], g2 = gcs[t*4+2], g3 = gcs[t*4+3];
    float mx = fmaxf(fmaxf(g0,g1), fmaxf(g2,g3));
    float e0 = __expf(g0-mx), e1 = __expf(g1-mx), e2 = __expf(g2-mx), e3 = __expf(g3-mx);
    float inv = 1.0f/(e0+e1+e2+e3);
    wgt[0][t*4+0]=e0*inv; wgt[0][t*4+1]=e1*inv; wgt[0][t*4+2]=e2*inv; wgt[0][t*4+3]=e3*inv;
  }

  for (int s=0; s<4; s++){
    const int Ycur = Y0 + s;

    // ---- phase 1: h1^T MFMA chain (all operands resident) -> A1 ----
    bf16x8 bk3[4];
    #pragma unroll
    for (int ct=0; ct<4; ct++){
      union { bf16x8 v; ushort sh[8]; } bb;
      #pragma unroll
      for (int j=0; j<8; j++) bb.sh[j] = 0;
      if (quad == 0){
        bb.sh[0] = f2bf(rmct[ct].relY);
        bb.sh[1] = f2bf(rmct[ct].relX);
        bb.sh[2] = 0x3F80u;
      }
      bk3[ct] = bb.v;
    }
    #pragma unroll
    for (int i=0; i<4; i++){
      int ncol0 = w*64 + i*16 + quad*4;
      #pragma unroll
      for (int ct=0; ct<4; ct++){
        const ushort* hp = &Ahr[(4*ct + (l15>>2))*136 + quad*8];
        f32x4 acc = f32x4{0.f,0.f,0.f,0.f};
        acc = __builtin_amdgcn_mfma_f32_16x16x32_bf16(a1f[i][0], ld8(hp +  0), acc, 0,0,0);
        acc = __builtin_amdgcn_mfma_f32_16x16x32_bf16(a1f[i][1], ld8(hp + 32), acc, 0,0,0);
        acc = __builtin_amdgcn_mfma_f32_16x16x32_bf16(a1f[i][2], ld8(hp + 64), acc, 0,0,0);
        acc = __builtin_amdgcn_mfma_f32_16x16x32_bf16(a1f[i][3], ld8(hp + 96), acc, 0,0,0);
        acc = __builtin_amdgcn_mfma_f32_16x16x32_bf16(a4f[i],    bk3[ct],      acc, 0,0,0);
        union { uint2 v; ushort sh[4]; } uu; uu.v = u4v[i][ct];
        int mrow = 16*ct + l15;
        uint2 o;
        o.x = (unsigned)f2bf(fmaxf(acc[0] + bf2f(uu.sh[0]), 0.f))
            | ((unsigned)f2bf(fmaxf(acc[1] + bf2f(uu.sh[1]), 0.f)) << 16);
        o.y = (unsigned)f2bf(fmaxf(acc[2] + bf2f(uu.sh[2]), 0.f))
            | ((unsigned)f2bf(fmaxf(acc[3] + bf2f(uu.sh[3]), 0.f)) << 16);
        *(uint2*)&A1[mrow*264 + ncol0] = o;
      }
    }
    __syncthreads();                                 // sync a

    // ---- prefetch next tile's globals (consumed next iteration) ----
    if (s < 3) prefetch_tile(Ycur + 1);

    // ---- layer 2: [64x256] @ W2 [256x128]; wave owns 32 N-cols ----
    f32x4 acc2[4][2];
    #pragma unroll
    for (int mt=0; mt<4; mt++)
      #pragma unroll
      for (int nt=0; nt<2; nt++) acc2[mt][nt] = f32x4{0.f,0.f,0.f,0.f};
    #pragma unroll
    for (int mt=0; mt<4; mt++)
      #pragma unroll
      for (int kt=0; kt<8; kt++){
        bf16x8 a = ld8(&A1[(mt*16 + l15)*264 + kt*32 + quad*8]);
        #pragma unroll
        for (int nt=0; nt<2; nt++)
          acc2[mt][nt] = __builtin_amdgcn_mfma_f32_16x16x32_bf16(a, b2f[kt][nt], acc2[mt][nt], 0,0,0);
      }
    __syncthreads();                                 // sync b

    // ---- h2 -> A1 alias; stage next tile's hr/gc; load W3 frags ----
    bf16x8 b3f[4][2];
    #pragma unroll
    for (int kt=0; kt<4; kt++)
      #pragma unroll
      for (int nt=0; nt<2; nt++)
        b3f[kt][nt] = ld8(&W3t[(size_t)(nt*16 + l15)*128 + kt*32 + quad*8]);
    {
      ushort* A2 = A1;
      float bias0 = b2v[w*32 + l15], bias1 = b2v[w*32 + 16 + l15];
      #pragma unroll
      for (int mt=0; mt<4; mt++)
        #pragma unroll
        for (int nt=0; nt<2; nt++){
          int n = w*32 + nt*16 + l15;
          float bv = nt ? bias1 : bias0;
          #pragma unroll
          for (int r=0; r<4; r++){
            int mm = mt*16 + quad*4 + r;
            A2[mm*136 + n] = f2bf(fmaxf(acc2[mt][nt][r] + bv, 0.0f));
          }
        }
    }
    if (s < 3) stage_tile();
    __syncthreads();                                 // sync c

    // ---- layer 3 + weighted epilogue; softmax for next tile ----
    {
      const ushort* A2 = A1;
      f32x4 acc3[2] = { f32x4{0.f,0.f,0.f,0.f}, f32x4{0.f,0.f,0.f,0.f} };
      #pragma unroll
      for (int kt=0; kt<4; kt++){
        bf16x8 a = ld8(&A2[(w*16 + l15)*136 + kt*32 + quad*8]);
        #pragma unroll
        for (int nt=0; nt<2; nt++)
          acc3[nt] = __builtin_amdgcn_mfma_f32_16x16x32_bf16(a, b3f[kt][nt], acc3[nt], 0,0,0);
      }
      int lp = w*4 + quad;               // pixel; rows m = w*16+quad*4+br
      int X = X0 + lp;
      const float* wp = wgt[s & 1];
      float w0 = wp[lp*4+0], w1 = wp[lp*4+1], w2 = wp[lp*4+2], w3 = wp[lp*4+3];
      #pragma unroll
      for (int nt=0; nt<2; nt++){
        int n = nt*16 + l15;
        float bb = b3v[n];
        float v = w0*(acc3[nt][0]+bb) + w1*(acc3[nt][1]+bb)
                + w2*(acc3[nt][2]+bb) + w3*(acc3[nt][3]+bb);
        outp[(size_t)n*65536 + (size_t)Ycur*256 + X] = v;
      }
    }
    if (s < 3 && t < 16){
      float g0 = gcs[t*4+0], g1 = gcs[t*4+1], g2 = gcs[t*4+2], g3 = gcs[t*4+3];
      float mx = fmaxf(fmaxf(g0,g1), fmaxf(g2,g3));
      float e0 = __expf(g0-mx), e1 = __expf(g1-mx), e2 = __expf(g2-mx), e3 = __expf(g3-mx);
      float inv = 1.0f/(e0+e1+e2+e3);
      int nb = (s+1) & 1;
      wgt[nb][t*4+0]=e0*inv; wgt[nb][t*4+1]=e1*inv;
      wgt[nb][t*4+2]=e2*inv; wgt[nb][t*4+3]=e3*inv;
    }
    __syncthreads();                                 // sync d (A1, wgt ready)
  }
}

extern "C" void kernel_launch(void* const* d_in, const int* in_sizes, int n_in,
                              void* d_out, int out_size, void* d_ws, size_t ws_size,
                              hipStream_t stream)
{
  const float* feat     = (const float*)d_in[0];
  const float* lr_guide = (const float*)d_in[1];
  const float* hr_guide = (const float*)d_in[2];
  const float* W1       = (const float*)d_in[3];
  const float* b1       = (const float*)d_in[4];
  const float* W2       = (const float*)d_in[5];
  const float* b2       = (const float*)d_in[6];
  const float* W3       = (const float*)d_in[7];
  const float* b3       = (const float*)d_in[8];
  float* outp = (float*)d_out;

  char* ws = (char*)d_ws;
  ushort* W1t = (ushort*)(ws);                 // 98304 el = 196608 B
  ushort* W2t = (ushort*)(ws + 196608);        // 32768 el = 65536 B
  ushort* W3t = (ushort*)(ws + 262144);        // 4096 el  = 8192 B
  ushort* Wx  = (ushort*)(ws + 270336);        // 8192 el  = 16384 B
  ushort* Ub  = (ushort*)(ws + 286720);        // 16388*256 el = 8390656 B
  ushort* Ubz = Ub + (size_t)16387*256;

  convert_weights<<<772, 256, 0, stream>>>(W1, b1, W2, W3, W1t, W2t, W3t, Wx, Ubz);
  stage1_gemm<<<1024, 256, 0, stream>>>(lr_guide, feat, W1t, Ub);
  main_fused<<<1024, 256, 0, stream>>>(feat, hr_guide, b2, b3,
                                       Ub, W1t, Wx, W2t, W3t, outp);
}

// Round 6
// 230.320 us; speedup vs baseline: 1.8669x; 1.8669x over previous
//
#include <hip/hip_runtime.h>
#include <hip/hip_bf16.h>

// ---------------------------------------------------------------------------
// BF_NIR_conv, round 6: R3 structure + C/D-layout U-add + layer-2 interleave.
//   U[pos][256] = featc[:,pos] @ W1[0:256,:]   (precomputed bf16; row 16387=0)
//   Per block (1x16 pixel row, 64 h1-rows = 16 pix x 4 branches):
//     h1^T[n][m] = sum_{k<128} W1[256+k][n]*hr[pix(m)][k]
//                + relY(m)*W1[384][n] + relX(m)*W1[385][n] + b1[n]  (Wx MFMA)
//                + U[spos(m)][n]                                    (C/D add)
//     h1 = relu -> LDS; h2 = relu(h1@W2+b2); pred = h2@W3+b3
//     out = softmax(gc)-weighted sum over branches
// ---------------------------------------------------------------------------

using bf16x8 = __attribute__((ext_vector_type(8))) __bf16;
using f32x4  = __attribute__((ext_vector_type(4))) float;

__device__ __forceinline__ float bf2f(unsigned short u){
  unsigned int x = ((unsigned int)u) << 16;
  return __builtin_bit_cast(float, x);
}
__device__ __forceinline__ unsigned short f2bf(float f){
  unsigned int x = __builtin_bit_cast(unsigned int, f);
  unsigned int r = x + 0x7fffu + ((x >> 16) & 1u);
  return (unsigned short)(r >> 16);
}
__device__ __forceinline__ bf16x8 ld8(const ushort* p){
  uint4 r = *(const uint4*)p;
  return __builtin_bit_cast(bf16x8, r);
}

struct RowMeta { int valid, ix; float relY, relX; int spos; };
__device__ __forceinline__ RowMeta row_meta(int Y, int X, int br){
  int ivx = br >> 1, ivy = br & 1;   // branch: (vx,vy)=(-,-),(-,+),(+,-),(+,+)
  int validY, iy; float relY;
  if (ivx == 0){ validY = (Y >= 1);   iy = (Y-1) >> 1; relY = (Y & 1) ?  0.5f :  1.5f; }
  else         { validY = (Y <= 254); iy = (Y+1) >> 1; relY = (Y & 1) ? -1.5f : -0.5f; }
  int validX, ix; float relX;
  if (ivy == 0){ validX = (X >= 1);   ix = (X-1) >> 1; relX = (X & 1) ?  0.5f :  1.5f; }
  else         { validX = (X <= 254); ix = (X+1) >> 1; relX = (X & 1) ? -1.5f : -0.5f; }
  RowMeta r;
  r.valid = validY && validX;
  r.ix = ix;
  if (r.valid){ r.relY = relY; r.relX = relX; r.spos = iy*128 + ix; }
  else { r.relY = (float)Y + 0.5f - 128.0f; r.relX = (float)X + 0.5f - 128.0f; r.spos = -1; }
  return r;
}

// --- kernel 0: weights -> bf16 N-major (R4 version: coalesced W1t writes) ----
__global__ __launch_bounds__(256) void convert_weights(
    const float* __restrict__ W1, const float* __restrict__ b1,
    const float* __restrict__ W2, const float* __restrict__ W3,
    ushort* __restrict__ W1t,   // [256][384]
    ushort* __restrict__ W2t,   // [128][256]
    ushort* __restrict__ W3t,   // [32][128]
    ushort* __restrict__ Wx,    // [256][32]: s0=W1[384][n], s1=W1[385][n], s2=b1[n]
    ushort* __restrict__ Ubz)   // Ub row 16387 (zeros)
{
  int b = blockIdx.x, t = threadIdx.x;
  if (b < 256){
    W1t[b*384 + t] = f2bf(W1[t*256 + b]);
    if (t < 128) W1t[b*384 + 256 + t] = f2bf(W1[(256+t)*256 + b]);
    if (t < 32){
      float v = (t==0) ? W1[384*256 + b] : (t==1) ? W1[385*256 + b]
              : (t==2) ? b1[b] : 0.0f;
      Wx[b*32 + t] = f2bf(v);
    }
    if (b < 128) W2t[b*256 + t] = f2bf(W2[t*128 + b]);
    if (b < 32 && t < 128) W3t[b*128 + t] = f2bf(W3[t*32 + b]);
  } else {
    Ubz[t] = 0;
  }
}

// --- kernel 1: U GEMM. M-tile 32, N-half 128, grid 1024 (R3 version). -------
__global__ __launch_bounds__(256) void stage1_gemm(
    const float* __restrict__ src0, const float* __restrict__ src1,  // lr_guide, feat
    const ushort* __restrict__ W1t,
    ushort* __restrict__ outp)                 // [16384][256]
{
  __shared__ ushort A[32*136];
  const int t = threadIdx.x;
  const int w = t >> 6, lane = t & 63, quad = lane >> 4, l15 = lane & 15;
  const int pos0  = (blockIdx.x >> 1) * 32;
  const int nside = (blockIdx.x & 1) * 128;
  const int mt = w >> 1;
  const int ntb = (w & 1) * 4;

  f32x4 acc[4];
  #pragma unroll
  for (int nt=0; nt<4; nt++) acc[nt] = f32x4{0.f,0.f,0.f,0.f};

  for (int h=0; h<2; h++){
    const float* src = h ? src1 : src0;
    #pragma unroll
    for (int i=0; i<16; i++){
      int f = i*256 + t;
      int k = f >> 5, mm = f & 31;
      A[mm*136 + k] = f2bf(src[(size_t)k*16384 + pos0 + mm]);
    }
    __syncthreads();
    #pragma unroll
    for (int kt=0; kt<4; kt++){
      bf16x8 a = ld8(&A[(mt*16 + l15)*136 + kt*32 + quad*8]);
      #pragma unroll
      for (int nt=0; nt<4; nt++){
        bf16x8 b = ld8(&W1t[(size_t)(nside + (ntb+nt)*16 + l15)*384 + h*128 + kt*32 + quad*8]);
        acc[nt] = __builtin_amdgcn_mfma_f32_16x16x32_bf16(a, b, acc[nt], 0,0,0);
      }
    }
    __syncthreads();
  }
  #pragma unroll
  for (int nt=0; nt<4; nt++){
    int n = nside + (ntb+nt)*16 + l15;
    #pragma unroll
    for (int r=0; r<4; r++){
      int mm = mt*16 + quad*4 + r;
      outp[(size_t)(pos0 + mm)*256 + n] = f2bf(acc[nt][r]);
    }
  }
}

// --- kernel 2: fused main (R3 phase structure) -------------------------------
__global__ __launch_bounds__(256, 4) void main_fused(
    const float* __restrict__ feat,      // [128][16384]
    const float* __restrict__ hr_guide,  // [128][65536]
    const float* __restrict__ b2v,
    const float* __restrict__ b3v,
    const ushort* __restrict__ Ub,       // [16388][256] bf16 (row 16387 zero)
    const ushort* __restrict__ W1t,      // [256][384] bf16 (N-major)
    const ushort* __restrict__ Wx,       // [256][32] rel/bias rows
    const ushort* __restrict__ W2t,      // [128][256] bf16 (N-major)
    const ushort* __restrict__ W3t,      // [32][128]  bf16 (N-major)
    float* __restrict__ outp)            // [32][65536]
{
  __shared__ __align__(16) ushort A1[64*264];   // h1 (stride 264); h2 aliases (stride 136)
  __shared__ __align__(16) ushort Ahr[16*136];  // hr tile [pix][ch]
  __shared__ float gcs[64];
  __shared__ float wgt[64];

  const int t = threadIdx.x;
  const int w = t >> 6, lane = t & 63, quad = lane >> 4, l15 = lane & 15;
  const int Y  = blockIdx.x >> 4;
  const int X0 = (blockIdx.x & 15) << 4;

  // ---- phase 0 (R3): hr staging + gc dots ----
  #pragma unroll
  for (int i=0; i<2; i++){
    int id = i*256 + t;                 // 0..511
    int ch = id >> 2, xq = id & 3;
    float4 v = *(const float4*)(hr_guide + (size_t)ch*65536 + Y*256 + X0 + xq*4);
    Ahr[(xq*4+0)*136 + ch] = f2bf(v.x);
    Ahr[(xq*4+1)*136 + ch] = f2bf(v.y);
    Ahr[(xq*4+2)*136 + ch] = f2bf(v.z);
    Ahr[(xq*4+3)*136 + ch] = f2bf(v.w);
  }
  if (t < 64){
    RowMeta g = row_meta(Y, X0 + (t>>2), t & 3);
    float gc = 0.0f;
    if (g.spos >= 0){
      int bpos = (Y>>1)*128 + ((X0 + (t>>2)) >> 1);
      #pragma unroll
      for (int cc=0; cc<3; cc++)
        gc += feat[(size_t)(124+cc)*16384 + bpos] * feat[(size_t)(124+cc)*16384 + g.spos];
    }
    gcs[t] = gc;
  }
  __syncthreads();                                   // sync1
  if (t < 16){
    float g0 = gcs[t*4+0], g1 = gcs[t*4+1], g2 = gcs[t*4+2], g3 = gcs[t*4+3];
    float mx = fmaxf(fmaxf(g0,g1), fmaxf(g2,g3));
    float e0 = __expf(g0-mx), e1 = __expf(g1-mx), e2 = __expf(g2-mx), e3 = __expf(g3-mx);
    float inv = 1.0f/(e0+e1+e2+e3);
    wgt[t*4+0]=e0*inv; wgt[t*4+1]=e1*inv; wgt[t*4+2]=e2*inv; wgt[t*4+3]=e3*inv;
  }

  // ---- phase 1: meta (after sync1, as R3), then h1^T MFMA -> A1 ----
  RowMeta rmct[4]; int urow[4];
  #pragma unroll
  for (int ct=0; ct<4; ct++){
    int m = 16*ct + l15;
    rmct[ct] = row_meta(Y, X0 + (m>>2), m & 3);
    urow[ct] = rmct[ct].spos >= 0 ? rmct[ct].spos : 16387;
  }
  bf16x8 bk3[4];
  #pragma unroll
  for (int ct=0; ct<4; ct++){
    union { bf16x8 v; ushort sh[8]; } bb;
    #pragma unroll
    for (int j=0; j<8; j++) bb.sh[j] = 0;
    if (quad == 0){
      bb.sh[0] = f2bf(rmct[ct].relY);
      bb.sh[1] = f2bf(rmct[ct].relX);
      bb.sh[2] = 0x3F80u;
    }
    bk3[ct] = bb.v;
  }
  #pragma unroll
  for (int i=0; i<4; i++){
    int n = w*64 + i*16 + l15;
    const ushort* wp = W1t + (size_t)n*384 + 256;
    bf16x8 a0 = ld8(wp + 0*32 + quad*8);
    bf16x8 a1 = ld8(wp + 1*32 + quad*8);
    bf16x8 a2 = ld8(wp + 2*32 + quad*8);
    bf16x8 a3 = ld8(wp + 3*32 + quad*8);
    bf16x8 a4 = ld8(&Wx[(size_t)n*32 + quad*8]);
    int ncol0 = w*64 + i*16 + quad*4;
    uint2 u4[4];
    #pragma unroll
    for (int ct=0; ct<4; ct++)
      u4[ct] = *(const uint2*)&Ub[(size_t)urow[ct]*256 + ncol0];
    // 4 independent accumulator chains (ct innermost)
    f32x4 acc[4];
    #pragma unroll
    for (int ct=0; ct<4; ct++) acc[ct] = f32x4{0.f,0.f,0.f,0.f};
    #pragma unroll
    for (int ct=0; ct<4; ct++)
      acc[ct] = __builtin_amdgcn_mfma_f32_16x16x32_bf16(a0, ld8(&Ahr[(4*ct+(l15>>2))*136 +  0 + quad*8]), acc[ct], 0,0,0);
    #pragma unroll
    for (int ct=0; ct<4; ct++)
      acc[ct] = __builtin_amdgcn_mfma_f32_16x16x32_bf16(a1, ld8(&Ahr[(4*ct+(l15>>2))*136 + 32 + quad*8]), acc[ct], 0,0,0);
    #pragma unroll
    for (int ct=0; ct<4; ct++)
      acc[ct] = __builtin_amdgcn_mfma_f32_16x16x32_bf16(a2, ld8(&Ahr[(4*ct+(l15>>2))*136 + 64 + quad*8]), acc[ct], 0,0,0);
    #pragma unroll
    for (int ct=0; ct<4; ct++)
      acc[ct] = __builtin_amdgcn_mfma_f32_16x16x32_bf16(a3, ld8(&Ahr[(4*ct+(l15>>2))*136 + 96 + quad*8]), acc[ct], 0,0,0);
    #pragma unroll
    for (int ct=0; ct<4; ct++)
      acc[ct] = __builtin_amdgcn_mfma_f32_16x16x32_bf16(a4, bk3[ct], acc[ct], 0,0,0);
    #pragma unroll
    for (int ct=0; ct<4; ct++){
      union { uint2 v; ushort sh[4]; } uu; uu.v = u4[ct];
      int mrow = 16*ct + l15;
      uint2 o;
      o.x = (unsigned)f2bf(fmaxf(acc[ct][0] + bf2f(uu.sh[0]), 0.f))
          | ((unsigned)f2bf(fmaxf(acc[ct][1] + bf2f(uu.sh[1]), 0.f)) << 16);
      o.y = (unsigned)f2bf(fmaxf(acc[ct][2] + bf2f(uu.sh[2]), 0.f))
          | ((unsigned)f2bf(fmaxf(acc[ct][3] + bf2f(uu.sh[3]), 0.f)) << 16);
      *(uint2*)&A1[mrow*264 + ncol0] = o;
    }
  }
  __syncthreads();                                   // sync2

  // ---- phase 2: layer 2 [64x256] @ W2 [256x128]; kt-outer, mt-inner ----
  bf16x8 b2f[8][2];
  #pragma unroll
  for (int kt=0; kt<8; kt++)
    #pragma unroll
    for (int nt=0; nt<2; nt++)
      b2f[kt][nt] = ld8(&W2t[(size_t)(w*32 + nt*16 + l15)*256 + kt*32 + quad*8]);

  f32x4 acc2[4][2];
  #pragma unroll
  for (int mt=0; mt<4; mt++)
    #pragma unroll
    for (int nt=0; nt<2; nt++) acc2[mt][nt] = f32x4{0.f,0.f,0.f,0.f};
  #pragma unroll
  for (int kt=0; kt<8; kt++)
    #pragma unroll
    for (int mt=0; mt<4; mt++){
      bf16x8 a = ld8(&A1[(mt*16 + l15)*264 + kt*32 + quad*8]);
      #pragma unroll
      for (int nt=0; nt<2; nt++)
        acc2[mt][nt] = __builtin_amdgcn_mfma_f32_16x16x32_bf16(a, b2f[kt][nt], acc2[mt][nt], 0,0,0);
    }
  __syncthreads();                                   // sync3 (A1 reads done)

  // ---- phase 3: h2 -> A1 alias (stride 136) ----
  {
    ushort* A2 = A1;
    float bias0 = b2v[w*32 + l15], bias1 = b2v[w*32 + 16 + l15];
    #pragma unroll
    for (int mt=0; mt<4; mt++)
      #pragma unroll
      for (int nt=0; nt<2; nt++){
        int n = w*32 + nt*16 + l15;
        float bv = nt ? bias1 : bias0;
        #pragma unroll
        for (int r=0; r<4; r++){
          int mm = mt*16 + quad*4 + r;
          A2[mm*136 + n] = f2bf(fmaxf(acc2[mt][nt][r] + bv, 0.0f));
        }
      }
  }
  __syncthreads();                                   // sync4

  // ---- phase 4: layer 3 [64x128] @ W3 [128x32] + weighted epilogue ----
  {
    bf16x8 b3f[4][2];
    #pragma unroll
    for (int kt=0; kt<4; kt++)
      #pragma unroll
      for (int nt=0; nt<2; nt++)
        b3f[kt][nt] = ld8(&W3t[(size_t)(nt*16 + l15)*128 + kt*32 + quad*8]);

    const ushort* A2 = A1;
    f32x4 acc3[2] = { f32x4{0.f,0.f,0.f,0.f}, f32x4{0.f,0.f,0.f,0.f} };
    #pragma unroll
    for (int kt=0; kt<4; kt++){
      bf16x8 a = ld8(&A2[(w*16 + l15)*136 + kt*32 + quad*8]);
      #pragma unroll
      for (int nt=0; nt<2; nt++)
        acc3[nt] = __builtin_amdgcn_mfma_f32_16x16x32_bf16(a, b3f[kt][nt], acc3[nt], 0,0,0);
    }
    int lp = w*4 + quad;                 // pixel; rows m = w*16+quad*4+br
    int X = X0 + lp;
    float w0 = wgt[lp*4+0], w1 = wgt[lp*4+1], w2 = wgt[lp*4+2], w3 = wgt[lp*4+3];
    #pragma unroll
    for (int nt=0; nt<2; nt++){
      int n = nt*16 + l15;
      float bb = b3v[n];
      float v = w0*(acc3[nt][0]+bb) + w1*(acc3[nt][1]+bb)
              + w2*(acc3[nt][2]+bb) + w3*(acc3[nt][3]+bb);
      outp[(size_t)n*65536 + (size_t)Y*256 + X] = v;
    }
  }
}

extern "C" void kernel_launch(void* const* d_in, const int* in_sizes, int n_in,
                              void* d_out, int out_size, void* d_ws, size_t ws_size,
                              hipStream_t stream)
{
  const float* feat     = (const float*)d_in[0];
  const float* lr_guide = (const float*)d_in[1];
  const float* hr_guide = (const float*)d_in[2];
  const float* W1       = (const float*)d_in[3];
  const float* b1       = (const float*)d_in[4];
  const float* W2       = (const float*)d_in[5];
  const float* b2       = (const float*)d_in[6];
  const float* W3       = (const float*)d_in[7];
  const float* b3       = (const float*)d_in[8];
  float* outp = (float*)d_out;

  char* ws = (char*)d_ws;
  ushort* W1t = (ushort*)(ws);                 // 98304 el = 196608 B
  ushort* W2t = (ushort*)(ws + 196608);        // 32768 el = 65536 B
  ushort* W3t = (ushort*)(ws + 262144);        // 4096 el  = 8192 B
  ushort* Wx  = (ushort*)(ws + 270336);        // 8192 el  = 16384 B
  ushort* Ub  = (ushort*)(ws + 286720);        // 16388*256 el = 8390656 B
  ushort* Ubz = Ub + (size_t)16387*256;

  convert_weights<<<257, 256, 0, stream>>>(W1, b1, W2, W3, W1t, W2t, W3t, Wx, Ubz);
  stage1_gemm<<<1024, 256, 0, stream>>>(lr_guide, feat, W1t, Ub);
  main_fused<<<4096, 256, 0, stream>>>(feat, hr_guide, b2, b3,
                                       Ub, W1t, Wx, W2t, W3t, outp);
}